// Round 1
// baseline (774.633 us; speedup 1.0000x reference)
//
#include <hip/hip_runtime.h>
#include <math.h>

#define N_NODES 4096
#define N_EDGES 8192
#define N_GRAPHS 256
#define D_NODE 64
#define D_EDGE 32
#define HH 256

// ---------------- workspace layout (float offsets) ----------------
// S region shared by S1 (4096x2112) and S2 (4096x8448) -- S1 consumed before S2 built.
static const size_t OFF_S   = 0;                 // 34,603,008 floats
static const size_t OFF_B1  = 34603008;          // 2112*256   = 540,672
static const size_t OFF_B2  = 35143680;          // 8448*256   = 2,162,688
static const size_t OFF_R   = 37306368;          // 4096*256 (R1 then reused as R2)
static const size_t OFF_H   = 38354944;          // 4096*256
static const size_t OFF_H2  = 39403520;          // 4096*256
static const size_t OFF_SUM = 40452096;          // 256*256
static const size_t OFF_CNT = 40517632;          // 256
static const size_t OFF_INT = 40517888;          // int region (indeg/starts/cursor/elist)
// total ~162.2 MB required in d_ws

// ---------------- CSR build ----------------
__global__ void count_k(const int* __restrict__ dst, int* __restrict__ indeg) {
    int e = blockIdx.x * 256 + threadIdx.x;
    if (e < N_EDGES) atomicAdd(&indeg[dst[e]], 1);
}

__global__ __launch_bounds__(1024) void scan_k(const int* __restrict__ indeg,
                                               int* __restrict__ starts) {
    __shared__ int part[1024];
    int t = threadIdx.x;
    int v[4]; int s = 0;
#pragma unroll
    for (int i = 0; i < 4; ++i) { v[i] = indeg[t * 4 + i]; s += v[i]; }
    part[t] = s;
    __syncthreads();
    for (int off = 1; off < 1024; off <<= 1) {
        int tv = (t >= off) ? part[t - off] : 0;
        __syncthreads();
        part[t] += tv;
        __syncthreads();
    }
    int excl = part[t] - s;
#pragma unroll
    for (int i = 0; i < 4; ++i) { starts[t * 4 + i] = excl; excl += v[i]; }
    if (t == 1023) starts[4096] = excl;
}

__global__ void fill_k(const int* __restrict__ dst, const int* __restrict__ starts,
                       int* __restrict__ cursor, int* __restrict__ elist) {
    int e = blockIdx.x * 256 + threadIdx.x;
    if (e < N_EDGES) {
        int d = dst[e];
        int p = atomicAdd(&cursor[d], 1);
        elist[starts[d] + p] = e;
    }
}

// ---------------- weight packing: W'[k*in+i][o], row 32*in+i = nn_b ----------------
__global__ void pack1_k(const float* __restrict__ w, const float* __restrict__ b,
                        float* __restrict__ B1) {
    int idx = blockIdx.x * 256 + threadIdx.x;     // < 2112*256
    int o = idx & 255; int kk = idx >> 8;
    int k = kk >> 6; int i = kk & 63;
    B1[idx] = (k < 32) ? w[k * (D_NODE * HH) + i * 256 + o] : b[i * 256 + o];
}

__global__ void pack2_k(const float* __restrict__ w, const float* __restrict__ b,
                        float* __restrict__ B2) {
    int idx = blockIdx.x * 256 + threadIdx.x;     // < 8448*256
    int o = idx & 255; int kk = idx >> 8;
    int k = kk >> 8; int i = kk & 255;
    B2[idx] = (k < 32) ? w[k * (HH * HH) + i * 256 + o] : b[i * 256 + o];
}

// ---------------- node outer-product accumulation ----------------
// S1[n, k*64 + i] = sum_{e: dst=n} ea'[e,k] * x[src[e], i],  ea'[:,32]=1
__global__ __launch_bounds__(64) void s1_k(const float* __restrict__ x,
                                           const float* __restrict__ ea,
                                           const int* __restrict__ src,
                                           const int* __restrict__ starts,
                                           const int* __restrict__ elist,
                                           float* __restrict__ S) {
    int n = blockIdx.x, t = threadIdx.x;
    __shared__ float sea[33];
    if (t == 32) sea[32] = 1.0f;
    float acc[33];
#pragma unroll
    for (int k = 0; k < 33; ++k) acc[k] = 0.f;
    int st = starts[n], en = starts[n + 1];
    for (int idx = st; idx < en; ++idx) {
        int e = elist[idx];
        int sn = src[e];
        if (t < 32) sea[t] = ea[e * 32 + t];
        __syncthreads();
        float xv = x[sn * 64 + t];
#pragma unroll
        for (int k = 0; k < 33; ++k) acc[k] += sea[k] * xv;
        __syncthreads();
    }
#pragma unroll
    for (int k = 0; k < 33; ++k) S[(size_t)n * 2112 + k * 64 + t] = acc[k];
}

// S2[n, k*256 + i] = sum_{e: dst=n} ea'[e,k] * h[src[e], i]
__global__ __launch_bounds__(256) void s2_k(const float* __restrict__ h,
                                            const float* __restrict__ ea,
                                            const int* __restrict__ src,
                                            const int* __restrict__ starts,
                                            const int* __restrict__ elist,
                                            float* __restrict__ S) {
    int n = blockIdx.x, t = threadIdx.x;
    __shared__ float sea[33];
    if (t == 32) sea[32] = 1.0f;
    float acc[33];
#pragma unroll
    for (int k = 0; k < 33; ++k) acc[k] = 0.f;
    int st = starts[n], en = starts[n + 1];
    for (int idx = st; idx < en; ++idx) {
        int e = elist[idx];
        int sn = src[e];
        if (t < 32) sea[t] = ea[e * 32 + t];
        __syncthreads();
        float hv = h[sn * 256 + t];
#pragma unroll
        for (int k = 0; k < 33; ++k) acc[k] += sea[k] * hv;
        __syncthreads();
    }
#pragma unroll
    for (int k = 0; k < 33; ++k) S[(size_t)n * 8448 + k * 256 + t] = acc[k];
}

// ---------------- generic fp32 GEMM: C = A[MxK] @ B[KxN] (+bias row)(+add)(relu) ----------------
__global__ __launch_bounds__(256)
void gemm64(const float* __restrict__ A, const float* __restrict__ B,
            const float* __restrict__ bias, const float* __restrict__ add,
            float* __restrict__ C, int M, int N, int K, int relu) {
    __shared__ float As[16][68];   // [k][m], padded to avoid bank conflicts
    __shared__ float Bs[16][68];   // [k][n]
    int tid = threadIdx.x;
    int bm = blockIdx.y, bn = blockIdx.x;
    int tm = (tid >> 4) << 2;          // 0..60
    int tn = (tid & 15) << 2;          // 0..60
    int arow = tid >> 2;               // 0..63
    int acol = (tid & 3) << 2;         // 0,4,8,12
    int brow = tid >> 4;               // 0..15
    int bcol = (tid & 15) << 2;        // 0..60
    float acc[4][4] = {};
    const float* Ap = A + (size_t)(bm * 64 + arow) * K + acol;
    const float* Bp = B + (size_t)brow * N + bn * 64 + bcol;
    for (int k0 = 0; k0 < K; k0 += 16) {
        float4 av = *(const float4*)(Ap + k0);
        float4 bv = *(const float4*)(Bp + (size_t)k0 * N);
        As[acol + 0][arow] = av.x;
        As[acol + 1][arow] = av.y;
        As[acol + 2][arow] = av.z;
        As[acol + 3][arow] = av.w;
        *(float4*)&Bs[brow][bcol] = bv;
        __syncthreads();
#pragma unroll
        for (int kk = 0; kk < 16; ++kk) {
            float4 a = *(const float4*)&As[kk][tm];
            float4 b = *(const float4*)&Bs[kk][tn];
            float ar[4] = {a.x, a.y, a.z, a.w};
            float br[4] = {b.x, b.y, b.z, b.w};
#pragma unroll
            for (int i = 0; i < 4; ++i)
#pragma unroll
                for (int j = 0; j < 4; ++j) acc[i][j] += ar[i] * br[j];
        }
        __syncthreads();
    }
#pragma unroll
    for (int i = 0; i < 4; ++i) {
        int m = bm * 64 + tm + i;
        int nbase = bn * 64 + tn;
#pragma unroll
        for (int j = 0; j < 4; ++j) {
            int n = nbase + j;
            float v = acc[i][j];
            if (bias) v += bias[n];
            if (add)  v += add[(size_t)m * N + n];
            if (relu) v = fmaxf(v, 0.f);
            C[(size_t)m * N + n] = v;
        }
    }
}

// ---------------- pooling + readout ----------------
__global__ __launch_bounds__(256) void pool_k(const float* __restrict__ h2,
                                              const int* __restrict__ batch,
                                              float* __restrict__ sums,
                                              float* __restrict__ cnts) {
    int n = blockIdx.x, t = threadIdx.x;
    int g = batch[n];
    atomicAdd(&sums[g * 256 + t], h2[(size_t)n * 256 + t]);
    if (t == 0) atomicAdd(&cnts[g], 1.0f);
}

__global__ __launch_bounds__(128) void readout_k(const float* __restrict__ sums,
                                                 const float* __restrict__ cnts,
                                                 const float* __restrict__ l1w,
                                                 const float* __restrict__ l1b,
                                                 const float* __restrict__ l2w,
                                                 const float* __restrict__ l2b,
                                                 float* __restrict__ out) {
    int g = blockIdx.x, t = threadIdx.x;
    __shared__ float sp[256];
    __shared__ float sz[128];
    float inv = 1.0f / fmaxf(cnts[g], 1.0f);
    sp[t]       = sums[g * 256 + t] * inv;
    sp[t + 128] = sums[g * 256 + 128 + t] * inv;
    __syncthreads();
    float a = l1b[t];
    for (int i = 0; i < 256; ++i) a += sp[i] * l1w[i * 128 + t];
    sz[t] = fmaxf(a, 0.f) * l2w[t];
    __syncthreads();
    for (int s = 64; s > 0; s >>= 1) {
        if (t < s) sz[t] += sz[t + s];
        __syncthreads();
    }
    if (t == 0) {
        float zz = sz[0] + l2b[0];
        out[g] = 1.0f / (1.0f + expf(-zz));
    }
}

extern "C" void kernel_launch(void* const* d_in, const int* in_sizes, int n_in,
                              void* d_out, int out_size, void* d_ws, size_t ws_size,
                              hipStream_t stream) {
    const float* x       = (const float*)d_in[0];
    const int*   ei      = (const int*)d_in[1];
    const float* ea      = (const float*)d_in[2];
    const int*   batch   = (const int*)d_in[3];
    const float* nn1_w   = (const float*)d_in[4];
    const float* nn1_b   = (const float*)d_in[5];
    const float* root1_w = (const float*)d_in[6];
    const float* bias1   = (const float*)d_in[7];
    const float* nn2_w   = (const float*)d_in[8];
    const float* nn2_b   = (const float*)d_in[9];
    const float* root2_w = (const float*)d_in[10];
    const float* bias2   = (const float*)d_in[11];
    const float* lin1_w  = (const float*)d_in[12];
    const float* lin1_b  = (const float*)d_in[13];
    const float* lin2_w  = (const float*)d_in[14];
    const float* lin2_b  = (const float*)d_in[15];
    float* out = (float*)d_out;
    float* ws  = (float*)d_ws;

    float* S    = ws + OFF_S;
    float* B1   = ws + OFF_B1;
    float* B2   = ws + OFF_B2;
    float* R    = ws + OFF_R;
    float* h    = ws + OFF_H;
    float* h2   = ws + OFF_H2;
    float* sums = ws + OFF_SUM;
    float* cnts = ws + OFF_CNT;
    int* ip     = (int*)(ws + OFF_INT);
    int* indeg  = ip;            // 4096
    int* starts = ip + 4096;     // 4097
    int* cursor = ip + 8200;     // 4096
    int* elist  = ip + 12304;    // 8192

    const int* srcv = ei;
    const int* dstv = ei + N_EDGES;

    hipMemsetAsync(indeg, 0, 4096 * 4, stream);
    hipMemsetAsync(cursor, 0, 4096 * 4, stream);
    hipMemsetAsync(sums, 0, 65536 * 4, stream);
    hipMemsetAsync(cnts, 0, 256 * 4, stream);

    count_k<<<32, 256, 0, stream>>>(dstv, indeg);
    scan_k<<<1, 1024, 0, stream>>>(indeg, starts);
    fill_k<<<32, 256, 0, stream>>>(dstv, starts, cursor, elist);

    pack1_k<<<2112, 256, 0, stream>>>(nn1_w, nn1_b, B1);
    pack2_k<<<8448, 256, 0, stream>>>(nn2_w, nn2_b, B2);

    // conv1
    s1_k<<<4096, 64, 0, stream>>>(x, ea, srcv, starts, elist, S);
    gemm64<<<dim3(4, 64), 256, 0, stream>>>(x, root1_w, bias1, nullptr, R,
                                            N_NODES, 256, 64, 0);        // R1 = x@root1 + b1
    gemm64<<<dim3(4, 64), 256, 0, stream>>>(S, B1, nullptr, R, h,
                                            N_NODES, 256, 2112, 1);      // h = relu(S1@W1' + R1)

    // conv2
    gemm64<<<dim3(4, 64), 256, 0, stream>>>(h, root2_w, bias2, nullptr, R,
                                            N_NODES, 256, 256, 0);       // R2 = h@root2 + b2
    s2_k<<<4096, 256, 0, stream>>>(h, ea, srcv, starts, elist, S);
    gemm64<<<dim3(4, 64), 256, 0, stream>>>(S, B2, nullptr, R, h2,
                                            N_NODES, 256, 8448, 0);      // h2 = S2@W2' + R2

    // pool + readout
    pool_k<<<4096, 256, 0, stream>>>(h2, batch, sums, cnts);
    readout_k<<<256, 128, 0, stream>>>(sums, cnts, lin1_w, lin1_b, lin2_w, lin2_b, out);
}

// Round 2
// 222.786 us; speedup vs baseline: 3.4770x; 3.4770x over previous
//
#include <hip/hip_runtime.h>
#include <math.h>

#define N_NODES 4096
#define N_EDGES 8192
#define N_GRAPHS 256
#define D_NODE 64
#define D_EDGE 32
#define HH 256

// K dims for the augmented factorized GEMMs (root + bias folded in)
#define K1 2176   // 33*64 (edge-MLP + nn_b) + 64 (x for root1)
#define K2 8704   // 33*256 + 256 (h for root2)

typedef _Float16 half8v __attribute__((ext_vector_type(8)));
typedef _Float16 half4v __attribute__((ext_vector_type(4)));
typedef float floatx4 __attribute__((ext_vector_type(4)));

// ---------------- workspace layout (float offsets) ----------------
static const size_t OFF_S    = 0;              // S' fp16: 4096 x 8704 halves = 17,825,792 floats (S1' shares)
static const size_t OFF_BT1  = 17825792;       // BT1 fp16: 256 x 2176 halves = 278,528 floats
static const size_t OFF_BT2  = 18104320;       // BT2 fp16: 256 x 8704 halves = 1,114,112 floats
static const size_t OFF_CP   = 19218432;       // Cpart fp32: 8 x 4096 x 256 = 8,388,608 floats
static const size_t OFF_H    = 27607040;       // h fp16: 4096 x 256 halves = 524,288 floats
static const size_t OFF_H2   = 28131328;       // h2 fp32: 1,048,576 floats
static const size_t OFF_POOL = 29179904;       // pooled fp32: 65,536 floats
static const size_t OFF_INT  = 29245440;       // int region
// total ~117 MB

// ---------------- CSR build ----------------
__global__ void count_k(const int* __restrict__ dst, int* __restrict__ indeg) {
    int e = blockIdx.x * 256 + threadIdx.x;
    if (e < N_EDGES) atomicAdd(&indeg[dst[e]], 1);
}

__global__ __launch_bounds__(1024) void scan_k(const int* __restrict__ indeg,
                                               int* __restrict__ starts) {
    __shared__ int part[1024];
    int t = threadIdx.x;
    int v[4]; int s = 0;
#pragma unroll
    for (int i = 0; i < 4; ++i) { v[i] = indeg[t * 4 + i]; s += v[i]; }
    part[t] = s;
    __syncthreads();
    for (int off = 1; off < 1024; off <<= 1) {
        int tv = (t >= off) ? part[t - off] : 0;
        __syncthreads();
        part[t] += tv;
        __syncthreads();
    }
    int excl = part[t] - s;
#pragma unroll
    for (int i = 0; i < 4; ++i) { starts[t * 4 + i] = excl; excl += v[i]; }
    if (t == 1023) starts[4096] = excl;
}

__global__ void fill_k(const int* __restrict__ dst, const int* __restrict__ starts,
                       int* __restrict__ cursor, int* __restrict__ elist) {
    int e = blockIdx.x * 256 + threadIdx.x;
    if (e < N_EDGES) {
        int d = dst[e];
        int p = atomicAdd(&cursor[d], 1);
        elist[starts[d] + p] = e;
    }
}

// ---------------- weight packing (transposed, fp16): BT[o][kk] ----------------
// LDS-tiled transpose: coalesced fp32 reads, coalesced fp16 writes.
__global__ __launch_bounds__(256) void packT1_k(const float* __restrict__ w,
                                                const float* __restrict__ b,
                                                const float* __restrict__ rw,
                                                _Float16* __restrict__ BT) {
    __shared__ float T[64][65];
    int t = threadIdx.x;
    int kk0 = blockIdx.x * 64, o0 = blockIdx.y * 64;
    int ol = t & 63, kb = t >> 6;
#pragma unroll
    for (int p = 0; p < 16; ++p) {
        int kl = p * 4 + kb;
        int kk = kk0 + kl, o = o0 + ol;
        float v;
        if (kk < 2048)       v = w[(kk >> 6) * 16384 + (kk & 63) * 256 + o];
        else if (kk < 2112)  v = b[(kk - 2048) * 256 + o];
        else                 v = rw[(kk - 2112) * 256 + o];
        T[kl][ol] = v;
    }
    __syncthreads();
    int kl2 = t & 63, ob = t >> 6;
#pragma unroll
    for (int p = 0; p < 16; ++p) {
        int ol2 = p * 4 + ob;
        BT[(size_t)(o0 + ol2) * K1 + kk0 + kl2] = (_Float16)T[kl2][ol2];
    }
}

__global__ __launch_bounds__(256) void packT2_k(const float* __restrict__ w,
                                                const float* __restrict__ b,
                                                const float* __restrict__ rw,
                                                _Float16* __restrict__ BT) {
    __shared__ float T[64][65];
    int t = threadIdx.x;
    int kk0 = blockIdx.x * 64, o0 = blockIdx.y * 64;
    int ol = t & 63, kb = t >> 6;
#pragma unroll
    for (int p = 0; p < 16; ++p) {
        int kl = p * 4 + kb;
        int kk = kk0 + kl, o = o0 + ol;
        float v;
        if (kk < 8192)       v = w[(kk >> 8) * 65536 + (kk & 255) * 256 + o];
        else if (kk < 8448)  v = b[(kk - 8192) * 256 + o];
        else                 v = rw[(kk - 8448) * 256 + o];
        T[kl][ol] = v;
    }
    __syncthreads();
    int kl2 = t & 63, ob = t >> 6;
#pragma unroll
    for (int p = 0; p < 16; ++p) {
        int ol2 = p * 4 + ob;
        BT[(size_t)(o0 + ol2) * K2 + kk0 + kl2] = (_Float16)T[kl2][ol2];
    }
}

// ---------------- node outer-product accumulation (fp16 out, augmented) ----------------
// S1'[n, k*64+i] = sum_{e:dst=n} ea'[e,k]*x[src[e],i];  S1'[n, 2112+i] = x[n,i]
__global__ __launch_bounds__(64) void s1_k(const float* __restrict__ x,
                                           const float* __restrict__ ea,
                                           const int* __restrict__ src,
                                           const int* __restrict__ starts,
                                           const int* __restrict__ elist,
                                           _Float16* __restrict__ S) {
    int n = blockIdx.x, t = threadIdx.x;
    __shared__ float sea[33];
    if (t == 32) sea[32] = 1.0f;
    float acc[33];
#pragma unroll
    for (int k = 0; k < 33; ++k) acc[k] = 0.f;
    int st = starts[n], en = starts[n + 1];
    for (int idx = st; idx < en; ++idx) {
        int e = elist[idx];
        int sn = src[e];
        if (t < 32) sea[t] = ea[e * 32 + t];
        __syncthreads();
        float xv = x[sn * 64 + t];
#pragma unroll
        for (int k = 0; k < 33; ++k) acc[k] += sea[k] * xv;
        __syncthreads();
    }
    _Float16* row = S + (size_t)n * K1;
#pragma unroll
    for (int k = 0; k < 33; ++k) row[k * 64 + t] = (_Float16)acc[k];
    row[2112 + t] = (_Float16)x[n * 64 + t];
}

// S2'[n, k*256+i] = sum_{e:dst=n} ea'[e,k]*h[src[e],i];  S2'[n, 8448+i] = h[n,i]
__global__ __launch_bounds__(256) void s2_k(const _Float16* __restrict__ h,
                                            const float* __restrict__ ea,
                                            const int* __restrict__ src,
                                            const int* __restrict__ starts,
                                            const int* __restrict__ elist,
                                            _Float16* __restrict__ S) {
    int n = blockIdx.x, t = threadIdx.x;
    __shared__ float sea[33];
    if (t == 32) sea[32] = 1.0f;
    float acc[33];
#pragma unroll
    for (int k = 0; k < 33; ++k) acc[k] = 0.f;
    int st = starts[n], en = starts[n + 1];
    for (int idx = st; idx < en; ++idx) {
        int e = elist[idx];
        int sn = src[e];
        if (t < 32) sea[t] = ea[e * 32 + t];
        __syncthreads();
        float hv = (float)h[sn * 256 + t];
#pragma unroll
        for (int k = 0; k < 33; ++k) acc[k] += sea[k] * hv;
        __syncthreads();
    }
    _Float16* row = S + (size_t)n * K2;
#pragma unroll
    for (int k = 0; k < 33; ++k) row[k * 256 + t] = (_Float16)acc[k];
    row[8448 + t] = h[n * 256 + t];
}

// ---------------- MFMA fp16 GEMM with split-K ----------------
// C_part[z] (128x128 tile) = A[M x K] @ BT[N x K]^T over K-slice z.
// 256 threads = 4 waves, each wave a 64x64 quadrant (4x4 MFMA 16x16x32 tiles).
// Swizzled LDS (slot = (chunk + r + (r>>2)) & 3) -> 2-way max bank aliasing (free).
__device__ __forceinline__ void async_copy16(const void* g, void* l) {
    __builtin_amdgcn_global_load_lds(
        (__attribute__((address_space(1))) unsigned int*)(g),
        (__attribute__((address_space(3))) unsigned int*)(l), 16, 0, 0);
}

__global__ __launch_bounds__(256) void gemm_f16(const _Float16* __restrict__ A,
                                                const _Float16* __restrict__ BT,
                                                float* __restrict__ Cpart,
                                                int K, int steps) {
    __shared__ _Float16 As[128 * 32];   // 8 KB: 128 rows x 64 B (swizzled 16B chunks)
    __shared__ _Float16 Bs[128 * 32];
    int tid = threadIdx.x;
    int w = tid >> 6, l = tid & 63;
    int mt = blockIdx.y, nt = blockIdx.x, z = blockIdx.z;
    int k0 = z * steps * 32;
    int wm = w & 1, wn = w >> 1;

    // --- staging setup: wave w stages rows [w*32, w*32+32) of both tiles ---
    int lr = l >> 2;
    int cc = ((l & 3) - lr - (lr >> 2)) & 3;   // global chunk fetched into slot l&3
    const _Float16* gA0 = A  + (size_t)(mt * 128 + w * 32 + lr)      * K + k0 + cc * 8;
    const _Float16* gA1 = A  + (size_t)(mt * 128 + w * 32 + 16 + lr) * K + k0 + cc * 8;
    const _Float16* gB0 = BT + (size_t)(nt * 128 + w * 32 + lr)      * K + k0 + cc * 8;
    const _Float16* gB1 = BT + (size_t)(nt * 128 + w * 32 + 16 + lr) * K + k0 + cc * 8;
    _Float16* lA0 = As + (w * 32) * 32;
    _Float16* lA1 = As + (w * 32 + 16) * 32;
    _Float16* lB0 = Bs + (w * 32) * 32;
    _Float16* lB1 = Bs + (w * 32 + 16) * 32;

    // --- fragment read setup ---
    int lm = l & 15, q = l >> 4;
    int slot = (q + lm + (lm >> 2)) & 3;
    const char* AsB = (const char*)As + (wm * 64 + lm) * 64 + slot * 16;
    const char* BsB = (const char*)Bs + (wn * 64 + lm) * 64 + slot * 16;

    floatx4 acc[4][4] = {};

    for (int s = 0; s < steps; ++s) {
        async_copy16(gA0, lA0);
        async_copy16(gA1, lA1);
        async_copy16(gB0, lB0);
        async_copy16(gB1, lB1);
        gA0 += 32; gA1 += 32; gB0 += 32; gB1 += 32;
        __syncthreads();
        half8v af[4], bf[4];
#pragma unroll
        for (int i = 0; i < 4; ++i) af[i] = *(const half8v*)(AsB + i * 1024);
#pragma unroll
        for (int j = 0; j < 4; ++j) bf[j] = *(const half8v*)(BsB + j * 1024);
#pragma unroll
        for (int i = 0; i < 4; ++i)
#pragma unroll
            for (int j = 0; j < 4; ++j)
                acc[i][j] = __builtin_amdgcn_mfma_f32_16x16x32_f16(af[i], bf[j], acc[i][j], 0, 0, 0);
        __syncthreads();
    }

    // epilogue: C/D layout col=lane&15, row=(lane>>4)*4+reg
    float* Cp = Cpart + (size_t)z * (N_NODES * HH);
    int m0 = mt * 128 + wm * 64;
    int n0 = nt * 128 + wn * 64 + lm;
#pragma unroll
    for (int i = 0; i < 4; ++i)
#pragma unroll
        for (int j = 0; j < 4; ++j)
#pragma unroll
            for (int r = 0; r < 4; ++r)
                Cp[(size_t)(m0 + i * 16 + q * 4 + r) * HH + n0 + j * 16] = acc[i][j][r];
}

// ---------------- split-K reduce + bias (+relu) ----------------
__global__ __launch_bounds__(256) void reduce_k(const float* __restrict__ Cp,
                                                const float* __restrict__ bias,
                                                _Float16* __restrict__ o16,
                                                float* __restrict__ o32,
                                                int nslices, int relu) {
    int idx = (blockIdx.x * 256 + threadIdx.x) * 4;
    float4 a = *(const float4*)(Cp + idx);
    for (int zz = 1; zz < nslices; ++zz) {
        float4 bq = *(const float4*)(Cp + (size_t)zz * (N_NODES * HH) + idx);
        a.x += bq.x; a.y += bq.y; a.z += bq.z; a.w += bq.w;
    }
    int n = idx & 255;
    float4 bb = *(const float4*)(bias + n);
    a.x += bb.x; a.y += bb.y; a.z += bb.z; a.w += bb.w;
    if (relu) {
        a.x = fmaxf(a.x, 0.f); a.y = fmaxf(a.y, 0.f);
        a.z = fmaxf(a.z, 0.f); a.w = fmaxf(a.w, 0.f);
    }
    if (o16) {
        half4v hv = {(_Float16)a.x, (_Float16)a.y, (_Float16)a.z, (_Float16)a.w};
        *(half4v*)(o16 + idx) = hv;
    } else {
        *(float4*)(o32 + idx) = a;
    }
}

// ---------------- mean pool (batch is sorted -> binary search, no atomics) ----------------
__global__ __launch_bounds__(256) void pool_k(const float* __restrict__ h2,
                                              const int* __restrict__ batch,
                                              float* __restrict__ pooled) {
    int g = blockIdx.x, t = threadIdx.x;
    __shared__ int bnds[2];
    if (t < 2) {
        int target = g + t;
        int lo = 0, hi = N_NODES;
        while (lo < hi) { int mid = (lo + hi) >> 1; if (batch[mid] < target) lo = mid + 1; else hi = mid; }
        bnds[t] = lo;
    }
    __syncthreads();
    int lo = bnds[0], hi = bnds[1];
    float s = 0.f;
    for (int n = lo; n < hi; ++n) s += h2[(size_t)n * 256 + t];
    float cnt = (float)(hi - lo);
    pooled[g * 256 + t] = s / fmaxf(cnt, 1.0f);
}

// ---------------- readout MLP ----------------
__global__ __launch_bounds__(128) void readout_k(const float* __restrict__ pooled,
                                                 const float* __restrict__ l1w,
                                                 const float* __restrict__ l1b,
                                                 const float* __restrict__ l2w,
                                                 const float* __restrict__ l2b,
                                                 float* __restrict__ out) {
    int g = blockIdx.x, t = threadIdx.x;
    __shared__ float sp[256];
    __shared__ float sz[128];
    sp[t]       = pooled[g * 256 + t];
    sp[t + 128] = pooled[g * 256 + 128 + t];
    __syncthreads();
    float a = l1b[t];
    for (int i = 0; i < 256; ++i) a += sp[i] * l1w[i * 128 + t];
    sz[t] = fmaxf(a, 0.f) * l2w[t];
    __syncthreads();
    for (int s = 64; s > 0; s >>= 1) {
        if (t < s) sz[t] += sz[t + s];
        __syncthreads();
    }
    if (t == 0) {
        float zz = sz[0] + l2b[0];
        out[g] = 1.0f / (1.0f + expf(-zz));
    }
}

extern "C" void kernel_launch(void* const* d_in, const int* in_sizes, int n_in,
                              void* d_out, int out_size, void* d_ws, size_t ws_size,
                              hipStream_t stream) {
    const float* x       = (const float*)d_in[0];
    const int*   ei      = (const int*)d_in[1];
    const float* ea      = (const float*)d_in[2];
    const int*   batch   = (const int*)d_in[3];
    const float* nn1_w   = (const float*)d_in[4];
    const float* nn1_b   = (const float*)d_in[5];
    const float* root1_w = (const float*)d_in[6];
    const float* bias1   = (const float*)d_in[7];
    const float* nn2_w   = (const float*)d_in[8];
    const float* nn2_b   = (const float*)d_in[9];
    const float* root2_w = (const float*)d_in[10];
    const float* bias2   = (const float*)d_in[11];
    const float* lin1_w  = (const float*)d_in[12];
    const float* lin1_b  = (const float*)d_in[13];
    const float* lin2_w  = (const float*)d_in[14];
    const float* lin2_b  = (const float*)d_in[15];
    float* out = (float*)d_out;
    float* ws  = (float*)d_ws;

    _Float16* S    = (_Float16*)(ws + OFF_S);
    _Float16* BT1  = (_Float16*)(ws + OFF_BT1);
    _Float16* BT2  = (_Float16*)(ws + OFF_BT2);
    float*    Cp   = ws + OFF_CP;
    _Float16* h    = (_Float16*)(ws + OFF_H);
    float*    h2   = ws + OFF_H2;
    float*    pooled = ws + OFF_POOL;
    int* ip     = (int*)(ws + OFF_INT);
    int* indeg  = ip;            // 4096
    int* starts = ip + 4096;     // 4097
    int* cursor = ip + 8200;     // 4096
    int* elist  = ip + 12304;    // 8192

    const int* srcv = ei;
    const int* dstv = ei + N_EDGES;

    hipMemsetAsync(indeg, 0, 4096 * 4, stream);
    hipMemsetAsync(cursor, 0, 4096 * 4, stream);

    count_k<<<32, 256, 0, stream>>>(dstv, indeg);
    scan_k<<<1, 1024, 0, stream>>>(indeg, starts);
    fill_k<<<32, 256, 0, stream>>>(dstv, starts, cursor, elist);

    packT1_k<<<dim3(K1 / 64, 4), 256, 0, stream>>>(nn1_w, nn1_b, root1_w, BT1);
    packT2_k<<<dim3(K2 / 64, 4), 256, 0, stream>>>(nn2_w, nn2_b, root2_w, BT2);

    // conv1: S1'[4096 x 2176] fp16, then MFMA GEMM (split-K=4, 17 steps/slice)
    s1_k<<<4096, 64, 0, stream>>>(x, ea, srcv, starts, elist, S);
    gemm_f16<<<dim3(2, 32, 4), 256, 0, stream>>>(S, BT1, Cp, K1, K1 / 32 / 4);
    reduce_k<<<1024, 256, 0, stream>>>(Cp, bias1, h, nullptr, 4, 1);   // h = relu(.)

    // conv2: S2'[4096 x 8704] fp16, MFMA GEMM (split-K=8, 34 steps/slice)
    s2_k<<<4096, 256, 0, stream>>>(h, ea, srcv, starts, elist, S);
    gemm_f16<<<dim3(2, 32, 8), 256, 0, stream>>>(S, BT2, Cp, K2, K2 / 32 / 8);
    reduce_k<<<1024, 256, 0, stream>>>(Cp, bias2, nullptr, h2, 8, 0);  // h2 fp32

    pool_k<<<N_GRAPHS, 256, 0, stream>>>(h2, batch, pooled);
    readout_k<<<N_GRAPHS, 128, 0, stream>>>(pooled, lin1_w, lin1_b, lin2_w, lin2_b, out);
}

// Round 3
// 206.901 us; speedup vs baseline: 3.7440x; 1.0768x over previous
//
#include <hip/hip_runtime.h>
#include <math.h>

#define N_NODES 4096
#define N_EDGES 8192
#define N_GRAPHS 256
#define D_NODE 64
#define D_EDGE 32
#define HH 256

// K dims for the augmented factorized GEMMs (root + bias folded in)
#define K1 2176   // 33*64 (edge-MLP + nn_b) + 64 (x for root1)
#define K2 8704   // 33*256 + 256 (h for root2)

typedef _Float16 half8v __attribute__((ext_vector_type(8)));
typedef _Float16 half4v __attribute__((ext_vector_type(4)));
typedef float floatx4 __attribute__((ext_vector_type(4)));

// ---------------- workspace layout (float offsets) ----------------
static const size_t OFF_S    = 0;              // S' fp16: 4096 x 8704 halves = 17,825,792 floats (S1' shares)
static const size_t OFF_BT1  = 17825792;       // BT1 fp16: 256 x 2176 halves = 278,528 floats
static const size_t OFF_BT2  = 18104320;       // BT2 fp16: 256 x 8704 halves = 1,114,112 floats
static const size_t OFF_CP   = 19218432;       // Cpart fp32: 12 x 4096 x 256 = 12,582,912 floats
static const size_t OFF_H    = 31801344;       // h fp16: 262,144 floats
static const size_t OFF_H2   = 32063488;       // h2 fp32: 1,048,576 floats
static const size_t OFF_INT  = 33112064;       // int region: starts[4097], elist[8192]
// total ~132.6 MB

// ---------------- CSR build: count+scan+fill+memsets in ONE single-block kernel ----------------
__global__ __launch_bounds__(1024) void csr_k(const int* __restrict__ dst,
                                              int* __restrict__ starts,
                                              int* __restrict__ elist) {
    __shared__ int cnt[4096];
    __shared__ int part[1024];
    int t = threadIdx.x;
#pragma unroll
    for (int i = 0; i < 4; ++i) cnt[t * 4 + i] = 0;
    __syncthreads();
#pragma unroll
    for (int i = 0; i < 8; ++i) atomicAdd(&cnt[dst[i * 1024 + t]], 1);
    __syncthreads();
    int v[4]; int s = 0;
#pragma unroll
    for (int i = 0; i < 4; ++i) { v[i] = cnt[t * 4 + i]; s += v[i]; }
    part[t] = s;
    __syncthreads();
    for (int off = 1; off < 1024; off <<= 1) {
        int tv = (t >= off) ? part[t - off] : 0;
        __syncthreads();
        part[t] += tv;
        __syncthreads();
    }
    int excl = part[t] - s;
    __syncthreads();                  // all reads of cnt done; safe to overwrite as cursor
#pragma unroll
    for (int i = 0; i < 4; ++i) {
        starts[t * 4 + i] = excl;
        cnt[t * 4 + i] = excl;        // cursor = starts
        excl += v[i];
    }
    if (t == 1023) starts[4096] = excl;
    __syncthreads();
#pragma unroll
    for (int i = 0; i < 8; ++i) {
        int e = i * 1024 + t;
        int d = dst[e];
        int p = atomicAdd(&cnt[d], 1);
        elist[p] = e;
    }
}

// ---------------- weight packing (transposed, fp16): BT[o][kk], both convs in one launch ----------------
__device__ __forceinline__ void packT_body(const float* __restrict__ w,
                                           const float* __restrict__ b,
                                           const float* __restrict__ rw,
                                           _Float16* __restrict__ BT,
                                           int kk0, int o0, int K,
                                           int wlim, int blim, int wshift, int wmask, int wrow) {
    __shared__ float T[64][65];
    int t = threadIdx.x;
    int ol = t & 63, kb = t >> 6;
#pragma unroll
    for (int p = 0; p < 16; ++p) {
        int kl = p * 4 + kb;
        int kk = kk0 + kl, o = o0 + ol;
        float v;
        if (kk < wlim)      v = w[(kk >> wshift) * wrow + (kk & wmask) * 256 + o];
        else if (kk < blim) v = b[(kk - wlim) * 256 + o];
        else                v = rw[(kk - blim) * 256 + o];
        T[kl][ol] = v;
    }
    __syncthreads();
    int kl2 = t & 63, ob = t >> 6;
#pragma unroll
    for (int p = 0; p < 16; ++p) {
        int ol2 = p * 4 + ob;
        BT[(size_t)(o0 + ol2) * K + kk0 + kl2] = (_Float16)T[kl2][ol2];
    }
}

__global__ __launch_bounds__(256) void pack_k(const float* __restrict__ w1,
                                              const float* __restrict__ b1,
                                              const float* __restrict__ r1,
                                              const float* __restrict__ w2,
                                              const float* __restrict__ b2,
                                              const float* __restrict__ r2,
                                              _Float16* __restrict__ BT1,
                                              _Float16* __restrict__ BT2) {
    int bx = blockIdx.x, o0 = blockIdx.y * 64;
    if (bx < K1 / 64)
        packT_body(w1, b1, r1, BT1, bx * 64, o0, K1, 2048, 2112, 6, 63, 16384);
    else
        packT_body(w2, b2, r2, BT2, (bx - K1 / 64) * 64, o0, K2, 8192, 8448, 8, 255, 65536);
}

// ---------------- node outer-product accumulation (fp16 out, augmented) ----------------
__global__ __launch_bounds__(64) void s1_k(const float* __restrict__ x,
                                           const float* __restrict__ ea,
                                           const int* __restrict__ src,
                                           const int* __restrict__ starts,
                                           const int* __restrict__ elist,
                                           _Float16* __restrict__ S) {
    int n = blockIdx.x, t = threadIdx.x;
    __shared__ float sea[33];
    if (t == 32) sea[32] = 1.0f;
    float acc[33];
#pragma unroll
    for (int k = 0; k < 33; ++k) acc[k] = 0.f;
    int st = starts[n], en = starts[n + 1];
    for (int idx = st; idx < en; ++idx) {
        int e = elist[idx];
        int sn = src[e];
        if (t < 32) sea[t] = ea[e * 32 + t];
        __syncthreads();
        float xv = x[sn * 64 + t];
#pragma unroll
        for (int k = 0; k < 33; ++k) acc[k] += sea[k] * xv;
        __syncthreads();
    }
    _Float16* row = S + (size_t)n * K1;
#pragma unroll
    for (int k = 0; k < 33; ++k) row[k * 64 + t] = (_Float16)acc[k];
    row[2112 + t] = (_Float16)x[n * 64 + t];
}

__global__ __launch_bounds__(256) void s2_k(const _Float16* __restrict__ h,
                                            const float* __restrict__ ea,
                                            const int* __restrict__ src,
                                            const int* __restrict__ starts,
                                            const int* __restrict__ elist,
                                            _Float16* __restrict__ S) {
    int n = blockIdx.x, t = threadIdx.x;
    __shared__ float sea[33];
    if (t == 32) sea[32] = 1.0f;
    float acc[33];
#pragma unroll
    for (int k = 0; k < 33; ++k) acc[k] = 0.f;
    int st = starts[n], en = starts[n + 1];
    for (int idx = st; idx < en; ++idx) {
        int e = elist[idx];
        int sn = src[e];
        if (t < 32) sea[t] = ea[e * 32 + t];
        __syncthreads();
        float hv = (float)h[sn * 256 + t];
#pragma unroll
        for (int k = 0; k < 33; ++k) acc[k] += sea[k] * hv;
        __syncthreads();
    }
    _Float16* row = S + (size_t)n * K2;
#pragma unroll
    for (int k = 0; k < 33; ++k) row[k * 256 + t] = (_Float16)acc[k];
    row[8448 + t] = h[n * 256 + t];
}

// ---------------- MFMA fp16 GEMM, BK=64, variable split-K ----------------
// C_part[z] (128x128 tile) = A @ BT^T over chunk range [z*NC/Z, (z+1)*NC/Z) of 64-wide K chunks.
// LDS row = 64 halves = 8 chunks of 16B; swizzle slot = chunk ^ (row&7) -> 2-way max aliasing.
__device__ __forceinline__ void async_copy16(const void* g, void* l) {
    __builtin_amdgcn_global_load_lds(
        (__attribute__((address_space(1))) unsigned int*)(g),
        (__attribute__((address_space(3))) unsigned int*)(l), 16, 0, 0);
}

__global__ __launch_bounds__(256, 3) void gemm_f16(const _Float16* __restrict__ A,
                                                   const _Float16* __restrict__ BT,
                                                   float* __restrict__ Cpart,
                                                   int K, int NC, int Z) {
    __shared__ _Float16 As[128 * 64];   // 16 KB
    __shared__ _Float16 Bs[128 * 64];   // 16 KB
    int tid = threadIdx.x;
    int w = tid >> 6, l = tid & 63;
    int mt = blockIdx.y, nt = blockIdx.x, z = blockIdx.z;
    int c0 = z * NC / Z, c1 = (z + 1) * NC / Z;
    int k0 = c0 * 64;
    int wm = w & 1, wn = w >> 1;

    // staging: wave w stages rows [w*32, w*32+32); issue q covers rows +q*8..+q*8+7
    int lr = l >> 3, lc = l & 7;
    int gc = lc ^ lr;                  // global chunk that lands in slot lc of row (..+lr)
    const _Float16* gA0 = A  + (size_t)(mt * 128 + w * 32 + lr) * K + k0 + gc * 8;
    const _Float16* gB0 = BT + (size_t)(nt * 128 + w * 32 + lr) * K + k0 + gc * 8;

    // fragment read setup
    int lm = l & 15, q4 = l >> 4;
    int sw = lm & 7;

    floatx4 acc[4][4] = {};

    for (int s = c0; s < c1; ++s) {
#pragma unroll
        for (int q = 0; q < 4; ++q) {
            async_copy16(gA0 + (size_t)q * 8 * K, As + (w * 32 + q * 8) * 64);
            async_copy16(gB0 + (size_t)q * 8 * K, Bs + (w * 32 + q * 8) * 64);
        }
        gA0 += 64; gB0 += 64;
        __syncthreads();
#pragma unroll
        for (int kw = 0; kw < 2; ++kw) {
            int ck = ((kw * 4 + q4) ^ sw) * 8;
            half8v af[4], bf[4];
#pragma unroll
            for (int i = 0; i < 4; ++i)
                af[i] = *(const half8v*)&As[(wm * 64 + i * 16 + lm) * 64 + ck];
#pragma unroll
            for (int j = 0; j < 4; ++j)
                bf[j] = *(const half8v*)&Bs[(wn * 64 + j * 16 + lm) * 64 + ck];
#pragma unroll
            for (int i = 0; i < 4; ++i)
#pragma unroll
                for (int j = 0; j < 4; ++j)
                    acc[i][j] = __builtin_amdgcn_mfma_f32_16x16x32_f16(af[i], bf[j], acc[i][j], 0, 0, 0);
        }
        __syncthreads();
    }

    // epilogue: C/D layout col=lane&15, row=(lane>>4)*4+reg
    float* Cp = Cpart + (size_t)z * (N_NODES * HH);
    int m0 = mt * 128 + wm * 64;
    int n0 = nt * 128 + wn * 64 + lm;
#pragma unroll
    for (int i = 0; i < 4; ++i)
#pragma unroll
        for (int j = 0; j < 4; ++j)
#pragma unroll
            for (int r = 0; r < 4; ++r)
                Cp[(size_t)(m0 + i * 16 + q4 * 4 + r) * HH + n0 + j * 16] = acc[i][j][r];
}

// ---------------- split-K reduce + bias (+relu) ----------------
__global__ __launch_bounds__(256) void reduce_k(const float* __restrict__ Cp,
                                                const float* __restrict__ bias,
                                                _Float16* __restrict__ o16,
                                                float* __restrict__ o32,
                                                int nslices, int relu) {
    int idx = (blockIdx.x * 256 + threadIdx.x) * 4;
    float4 a = *(const float4*)(Cp + idx);
    for (int zz = 1; zz < nslices; ++zz) {
        float4 bq = *(const float4*)(Cp + (size_t)zz * (N_NODES * HH) + idx);
        a.x += bq.x; a.y += bq.y; a.z += bq.z; a.w += bq.w;
    }
    int n = idx & 255;
    float4 bb = *(const float4*)(bias + n);
    a.x += bb.x; a.y += bb.y; a.z += bb.z; a.w += bb.w;
    if (relu) {
        a.x = fmaxf(a.x, 0.f); a.y = fmaxf(a.y, 0.f);
        a.z = fmaxf(a.z, 0.f); a.w = fmaxf(a.w, 0.f);
    }
    if (o16) {
        half4v hv = {(_Float16)a.x, (_Float16)a.y, (_Float16)a.z, (_Float16)a.w};
        *(half4v*)(o16 + idx) = hv;
    } else {
        *(float4*)(o32 + idx) = a;
    }
}

// ---------------- fused mean-pool + readout MLP ----------------
__global__ __launch_bounds__(128) void poolread_k(const float* __restrict__ h2,
                                                  const int* __restrict__ batch,
                                                  const float* __restrict__ l1w,
                                                  const float* __restrict__ l1b,
                                                  const float* __restrict__ l2w,
                                                  const float* __restrict__ l2b,
                                                  float* __restrict__ out) {
    int g = blockIdx.x, t = threadIdx.x;
    __shared__ int bnds[2];
    __shared__ float sp[256];
    __shared__ float sz[128];
    if (t < 2) {
        int target = g + t;
        int lo = 0, hi = N_NODES;
        while (lo < hi) { int mid = (lo + hi) >> 1; if (batch[mid] < target) lo = mid + 1; else hi = mid; }
        bnds[t] = lo;
    }
    __syncthreads();
    int lo = bnds[0], hi = bnds[1];
    float s0 = 0.f, s1 = 0.f;
    for (int n = lo; n < hi; ++n) {
        s0 += h2[(size_t)n * 256 + t];
        s1 += h2[(size_t)n * 256 + 128 + t];
    }
    float inv = 1.0f / fmaxf((float)(hi - lo), 1.0f);
    sp[t] = s0 * inv;
    sp[t + 128] = s1 * inv;
    __syncthreads();
    float a = l1b[t];
#pragma unroll 8
    for (int i = 0; i < 256; ++i) a += sp[i] * l1w[i * 128 + t];
    sz[t] = fmaxf(a, 0.f) * l2w[t];
    __syncthreads();
    for (int s = 64; s > 0; s >>= 1) {
        if (t < s) sz[t] += sz[t + s];
        __syncthreads();
    }
    if (t == 0) {
        float zz = sz[0] + l2b[0];
        out[g] = 1.0f / (1.0f + expf(-zz));
    }
}

extern "C" void kernel_launch(void* const* d_in, const int* in_sizes, int n_in,
                              void* d_out, int out_size, void* d_ws, size_t ws_size,
                              hipStream_t stream) {
    const float* x       = (const float*)d_in[0];
    const int*   ei      = (const int*)d_in[1];
    const float* ea      = (const float*)d_in[2];
    const int*   batch   = (const int*)d_in[3];
    const float* nn1_w   = (const float*)d_in[4];
    const float* nn1_b   = (const float*)d_in[5];
    const float* root1_w = (const float*)d_in[6];
    const float* bias1   = (const float*)d_in[7];
    const float* nn2_w   = (const float*)d_in[8];
    const float* nn2_b   = (const float*)d_in[9];
    const float* root2_w = (const float*)d_in[10];
    const float* bias2   = (const float*)d_in[11];
    const float* lin1_w  = (const float*)d_in[12];
    const float* lin1_b  = (const float*)d_in[13];
    const float* lin2_w  = (const float*)d_in[14];
    const float* lin2_b  = (const float*)d_in[15];
    float* out = (float*)d_out;
    float* ws  = (float*)d_ws;

    _Float16* S    = (_Float16*)(ws + OFF_S);
    _Float16* BT1  = (_Float16*)(ws + OFF_BT1);
    _Float16* BT2  = (_Float16*)(ws + OFF_BT2);
    float*    Cp   = ws + OFF_CP;
    _Float16* h    = (_Float16*)(ws + OFF_H);
    float*    h2   = ws + OFF_H2;
    int* ip     = (int*)(ws + OFF_INT);
    int* starts = ip;            // 4097
    int* elist  = ip + 4100;     // 8192

    const int* srcv = ei;
    const int* dstv = ei + N_EDGES;

    csr_k<<<1, 1024, 0, stream>>>(dstv, starts, elist);
    pack_k<<<dim3(K1 / 64 + K2 / 64, 4), 256, 0, stream>>>(nn1_w, nn1_b, root1_w,
                                                           nn2_w, nn2_b, root2_w, BT1, BT2);

    // conv1: S1'[4096 x 2176] fp16, MFMA GEMM BK=64, split-K=8 (chunks 34 -> slices 4/5)
    s1_k<<<4096, 64, 0, stream>>>(x, ea, srcv, starts, elist, S);
    gemm_f16<<<dim3(2, 32, 8), 256, 0, stream>>>(S, BT1, Cp, K1, K1 / 64, 8);
    reduce_k<<<1024, 256, 0, stream>>>(Cp, bias1, h, nullptr, 8, 1);    // h = relu(.)

    // conv2: S2'[4096 x 8704] fp16, MFMA GEMM BK=64, split-K=12 (chunks 136 -> slices 11/12)
    s2_k<<<4096, 256, 0, stream>>>(h, ea, srcv, starts, elist, S);
    gemm_f16<<<dim3(2, 32, 12), 256, 0, stream>>>(S, BT2, Cp, K2, K2 / 64, 12);
    reduce_k<<<1024, 256, 0, stream>>>(Cp, bias2, nullptr, h2, 12, 0);  // h2 fp32

    poolread_k<<<N_GRAPHS, 128, 0, stream>>>(h2, batch, lin1_w, lin1_b, lin2_w, lin2_b, out);
}